// Round 1
// baseline (1190.866 us; speedup 1.0000x reference)
//
#include <hip/hip_runtime.h>

// ISNELayer: out[t] = mean_{e: tgt[e]==t} emb[node_ids[src[e]]]
// N=100000 nodes, H=128 hidden, E=625000 edges, all fp32 (indices int32).

#define NUM_NODES 100000
#define HIDDEN 128
#define NUM_EDGES 625000

// 32 lanes cooperate on one edge; each lane handles 4 contiguous floats (float4).
__global__ __launch_bounds__(256) void isne_scatter_kernel(
    const int* __restrict__ node_ids,
    const int* __restrict__ edge_src,   // edge_index row 0
    const int* __restrict__ edge_tgt,   // edge_index row 1
    const float* __restrict__ emb,
    float* __restrict__ out,            // pre-zeroed, accumulates sums
    float* __restrict__ counts)         // pre-zeroed [NUM_NODES]
{
    int gid  = blockIdx.x * blockDim.x + threadIdx.x;
    int edge = gid >> 5;
    int lane = gid & 31;
    if (edge >= NUM_EDGES) return;

    int src_idx = edge_src[edge];
    int src     = node_ids[src_idx];   // node_ids is arange, but follow the reference
    int tgt     = edge_tgt[edge];

    const float4 v = *reinterpret_cast<const float4*>(
        emb + (size_t)src * HIDDEN + lane * 4);
    float* o = out + (size_t)tgt * HIDDEN + lane * 4;
    atomicAdd(o + 0, v.x);
    atomicAdd(o + 1, v.y);
    atomicAdd(o + 2, v.z);
    atomicAdd(o + 3, v.w);
    if (lane == 0) atomicAdd(counts + tgt, 1.0f);
}

// One thread per float4 group of out; HIDDEN/4 = 32 groups per node.
__global__ __launch_bounds__(256) void isne_divide_kernel(
    float* __restrict__ out,
    const float* __restrict__ counts)
{
    int gid = blockIdx.x * blockDim.x + threadIdx.x;
    if (gid >= NUM_NODES * (HIDDEN / 4)) return;
    int node = gid >> 5;                       // gid / (HIDDEN/4)
    float c   = counts[node];
    float inv = 1.0f / fmaxf(c, 1.0f);
    float4* p = reinterpret_cast<float4*>(out) + gid;
    float4 v  = *p;
    v.x *= inv; v.y *= inv; v.z *= inv; v.w *= inv;
    *p = v;
}

extern "C" void kernel_launch(void* const* d_in, const int* in_sizes, int n_in,
                              void* d_out, int out_size, void* d_ws, size_t ws_size,
                              hipStream_t stream) {
    const int*   node_ids = (const int*)d_in[0];
    const int*   edge_idx = (const int*)d_in[1];   // [2, E] flat: row0 = src, row1 = tgt
    const float* emb      = (const float*)d_in[2];
    float*       out      = (float*)d_out;         // [N, H] fp32
    float*       counts   = (float*)d_ws;          // [N] fp32 scratch

    const int* edge_src = edge_idx;
    const int* edge_tgt = edge_idx + NUM_EDGES;

    // Harness poisons d_out / d_ws with 0xAA before every timed launch:
    // zero the accumulators ourselves (memset nodes are graph-capturable).
    hipMemsetAsync(out, 0, (size_t)out_size * sizeof(float), stream);
    hipMemsetAsync(counts, 0, (size_t)NUM_NODES * sizeof(float), stream);

    {
        // 32 threads per edge
        long long total = (long long)NUM_EDGES * 32;
        int block = 256;
        int grid  = (int)((total + block - 1) / block);
        isne_scatter_kernel<<<grid, block, 0, stream>>>(
            node_ids, edge_src, edge_tgt, emb, out, counts);
    }
    {
        int total = NUM_NODES * (HIDDEN / 4);
        int block = 256;
        int grid  = (total + block - 1) / block;
        isne_divide_kernel<<<grid, block, 0, stream>>>(out, counts);
    }
}

// Round 2
// 207.696 us; speedup vs baseline: 5.7337x; 5.7337x over previous
//
#include <hip/hip_runtime.h>

// ISNELayer: out[t] = mean_{e: tgt[e]==t} emb[node_ids[src[e]]]
// Strategy: counting-sort edges by target, then register-accumulate gather.
// Eliminates the 1.3 GB of fp32 atomic write-through traffic seen in R1.

#define NUM_NODES 100000
#define HIDDEN    128
#define NUM_EDGES 625000
#define SCAN_BLOCK 256
#define NBLK ((NUM_NODES + SCAN_BLOCK - 1) / SCAN_BLOCK)   // 391

// --- 1. histogram of targets -------------------------------------------------
__global__ __launch_bounds__(256) void hist_kernel(
    const int* __restrict__ tgt, int* __restrict__ cnt)
{
    int e = blockIdx.x * blockDim.x + threadIdx.x;
    if (e < NUM_EDGES) atomicAdd(&cnt[tgt[e]], 1);
}

// --- 2a. per-block exclusive scan -------------------------------------------
__global__ __launch_bounds__(SCAN_BLOCK) void scan1_kernel(
    const int* __restrict__ cnt, int* __restrict__ excl, int* __restrict__ bsum)
{
    __shared__ int s[SCAN_BLOCK];
    int i = blockIdx.x * SCAN_BLOCK + threadIdx.x;
    int v = (i < NUM_NODES) ? cnt[i] : 0;
    s[threadIdx.x] = v; __syncthreads();
    for (int d = 1; d < SCAN_BLOCK; d <<= 1) {
        int t = (threadIdx.x >= (unsigned)d) ? s[threadIdx.x - d] : 0;
        __syncthreads();
        s[threadIdx.x] += t;
        __syncthreads();
    }
    if (i < NUM_NODES) excl[i] = s[threadIdx.x] - v;
    if (threadIdx.x == SCAN_BLOCK - 1) bsum[blockIdx.x] = s[threadIdx.x];
}

// --- 2b. scan of the 391 block sums (single block) ---------------------------
__global__ __launch_bounds__(512) void scan2_kernel(
    const int* __restrict__ bsum, int* __restrict__ boff)
{
    __shared__ int s[512];
    int i = threadIdx.x;
    int v = (i < NBLK) ? bsum[i] : 0;
    s[i] = v; __syncthreads();
    for (int d = 1; d < 512; d <<= 1) {
        int t = (i >= d) ? s[i - d] : 0;
        __syncthreads();
        s[i] += t;
        __syncthreads();
    }
    if (i < NBLK) boff[i] = s[i] - v;
}

// --- 2c. finalize offsets, init cursors -------------------------------------
__global__ __launch_bounds__(256) void scan3_kernel(
    const int* __restrict__ excl, const int* __restrict__ boff,
    int* __restrict__ offsets, int* __restrict__ cursor)
{
    int i = blockIdx.x * blockDim.x + threadIdx.x;
    if (i < NUM_NODES) {
        int o = excl[i] + boff[i >> 8];   // 256 elements per scan1 block
        offsets[i] = o;
        cursor[i]  = o;
    }
    if (i == 0) offsets[NUM_NODES] = NUM_EDGES;
}

// --- 3. permute: bucket source node ids by target ----------------------------
__global__ __launch_bounds__(256) void permute_kernel(
    const int* __restrict__ node_ids, const int* __restrict__ src,
    const int* __restrict__ tgt, int* __restrict__ cursor,
    int* __restrict__ sorted_src)
{
    int e = blockIdx.x * blockDim.x + threadIdx.x;
    if (e < NUM_EDGES) {
        int pos = atomicAdd(&cursor[tgt[e]], 1);
        sorted_src[pos] = node_ids[src[e]];
    }
}

// --- 4. gather-mean: 32 lanes per output row, register accumulation ----------
__global__ __launch_bounds__(256) void gather_kernel(
    const int* __restrict__ offsets, const int* __restrict__ sorted_src,
    const float* __restrict__ emb, float* __restrict__ out)
{
    int gid  = blockIdx.x * blockDim.x + threadIdx.x;
    int n    = gid >> 5;
    int lane = gid & 31;
    if (n >= NUM_NODES) return;

    int beg = offsets[n], end = offsets[n + 1];
    float4 acc = make_float4(0.f, 0.f, 0.f, 0.f);
    int i = beg;
    for (; i + 1 < end; i += 2) {            // 2 loads in flight
        int s0 = sorted_src[i], s1 = sorted_src[i + 1];
        const float4 a = *reinterpret_cast<const float4*>(
            emb + (size_t)s0 * HIDDEN + lane * 4);
        const float4 b = *reinterpret_cast<const float4*>(
            emb + (size_t)s1 * HIDDEN + lane * 4);
        acc.x += a.x + b.x; acc.y += a.y + b.y;
        acc.z += a.z + b.z; acc.w += a.w + b.w;
    }
    if (i < end) {
        int s0 = sorted_src[i];
        const float4 a = *reinterpret_cast<const float4*>(
            emb + (size_t)s0 * HIDDEN + lane * 4);
        acc.x += a.x; acc.y += a.y; acc.z += a.z; acc.w += a.w;
    }
    float inv = (end > beg) ? 1.0f / (float)(end - beg) : 0.0f;
    float4 r = make_float4(acc.x * inv, acc.y * inv, acc.z * inv, acc.w * inv);
    *reinterpret_cast<float4*>(out + (size_t)n * HIDDEN + lane * 4) = r;
}

extern "C" void kernel_launch(void* const* d_in, const int* in_sizes, int n_in,
                              void* d_out, int out_size, void* d_ws, size_t ws_size,
                              hipStream_t stream) {
    const int*   node_ids = (const int*)d_in[0];
    const int*   edge_idx = (const int*)d_in[1];   // [2, E]: row0 src, row1 tgt
    const float* emb      = (const float*)d_in[2];
    float*       out      = (float*)d_out;

    const int* edge_src = edge_idx;
    const int* edge_tgt = edge_idx + NUM_EDGES;

    // workspace layout (bytes)
    char* ws = (char*)d_ws;
    int* cnt        = (int*)(ws + 0);                 // 400000
    int* excl       = (int*)(ws + 400000);            // 400000
    int* bsum       = (int*)(ws + 800000);            // 2048 (NBLK=391)
    int* boff       = (int*)(ws + 802048);            // 2048
    int* offsets    = (int*)(ws + 804096);            // 400008 (N+1)
    int* cursor     = (int*)(ws + 1204104);           // 400000
    int* sorted_src = (int*)(ws + 1604104);           // 2500000
    // total ~4.1 MB

    hipMemsetAsync(cnt, 0, NUM_NODES * sizeof(int), stream);

    int eb = (NUM_EDGES + 255) / 256;
    hist_kernel<<<eb, 256, 0, stream>>>(edge_tgt, cnt);
    scan1_kernel<<<NBLK, SCAN_BLOCK, 0, stream>>>(cnt, excl, bsum);
    scan2_kernel<<<1, 512, 0, stream>>>(bsum, boff);
    scan3_kernel<<<NBLK, 256, 0, stream>>>(excl, boff, offsets, cursor);
    permute_kernel<<<eb, 256, 0, stream>>>(node_ids, edge_src, edge_tgt,
                                           cursor, sorted_src);
    {
        long long total = (long long)NUM_NODES * 32;
        int grid = (int)((total + 255) / 256);
        gather_kernel<<<grid, 256, 0, stream>>>(offsets, sorted_src, emb, out);
    }
}